// Round 8
// baseline (1869.088 us; speedup 1.0000x reference)
//
#include <hip/hip_runtime.h>

// ---------------------------------------------------------------------------
// Round 8: 2 waves/SIMD with independent work (stall filling).
// 64 blocks x 512 threads, BB=32 batch per block.
// Encoder: wave (lw,grp) = layer lw, col-half grp; handles both 16-batch tiles.
// Decoder: two independent 16-batch groups (waves 0-3 / 4-7), each R7-style
// col-sliced fire+prec with fused projection.
// c hand-off through a flat LDS region aliased onto Hb (barrier-sequenced).
// ---------------------------------------------------------------------------

#define S_LEN 120
#define BATCH 2048
#define NIN   6
#define H     64
#define NL    4
#define TLEN  120
#define BB    32

#define HPAD 72            // row stride in halves (144 B)

#define FRAGS_HALF 60      // col-sliced: 12 (layer0) + 3*16
#define PACK_H8    (2 * FRAGS_HALF * 4 * 64)
#define PROJ_H8    (2 * 64)
#define NPACK      ((PACK_H8 + PROJ_H8) * 8)   // 246784 fp16 elements
#define EPACK_EL   (256 * 64 * 8)              // encoder pipeline pack
#define NTOT       (NPACK + EPACK_EL)

#define PERM(kk) ((((kk) & 3) << 4) | ((kk) >> 2))   // pi^-1
#define PI(c)    ((((c) & 15) << 2) | ((c) >> 4))    // pi

typedef _Float16 h8    __attribute__((ext_vector_type(8)));
typedef _Float16 hh2   __attribute__((ext_vector_type(2)));
typedef float    f32x4 __attribute__((ext_vector_type(4)));

__device__ __forceinline__ void bar_lgkm() {
  asm volatile("s_waitcnt lgkmcnt(0)\n\ts_barrier" ::: "memory");
}

// ---------------------------------------------------------------------------
// Weight pack (identical to rounds 5-7).
// ---------------------------------------------------------------------------
__global__ void prep_weights(const float* __restrict__ eWih0,
                             const float* __restrict__ eWih,
                             const float* __restrict__ eWhh,
                             const float* __restrict__ dWih0,
                             const float* __restrict__ dWih,
                             const float* __restrict__ dWhh,
                             const float* __restrict__ linW,
                             _Float16* __restrict__ wq) {
  int idx = blockIdx.x * blockDim.x + threadIdx.x;
  if (idx >= NTOT) return;

  if (idx >= NPACK) {                      // ---- encoder pipeline pack ----
    int p    = idx - NPACK;
    int j    = p & 7;
    int lane = (p >> 3) & 63;
    int fe   = p >> 9;
    int kt   = fe & 3, nt = (fe >> 2) & 15, l = fe >> 6;
    int g    = nt * 16 + (lane & 15);
    int koff = ((lane >> 4) << 3) + j;
    float v = 0.0f;
    if (l == 0) {
      if (kt == 0)      v = (koff < NIN) ? eWih0[g * NIN + koff] : 0.0f;
      else if (kt == 1) v = 0.0f;
      else { int kk = (kt - 2) * 32 + koff; v = eWhh[g * H + PERM(kk)]; }
    } else {
      if (kt < 2) { int kk = kt * 32 + koff;
                    v = eWih[((l - 1) * 256 + g) * H + PERM(kk)]; }
      else        { int kk = (kt - 2) * 32 + koff;
                    v = eWhh[(l * 256 + g) * H + PERM(kk)]; }
    }
    wq[idx] = (_Float16)v;
    return;
  }

  if (idx >= PACK_H8 * 8) {                // ---- linW A-layout frags ----
    int p    = idx - PACK_H8 * 8;
    int j    = p & 7;
    int lane = (p >> 3) & 63;
    int fr   = p >> 9;
    int m    = lane & 15;
    int k    = fr * 32 + ((lane >> 4) << 3) + j;
    wq[idx] = (_Float16)((m < NIN) ? linW[m * H + k] : 0.0f);
    return;
  }

  // ---- col-sliced pack (decoder uses dec half) ----
  const int j    = idx & 7;
  const int lane = (idx >> 3) & 63;
  const int wv   = (idx >> 9) & 3;
  const int fh   = idx >> 11;
  const int f    = fh % FRAGS_HALF;
  const int half = fh / FRAGS_HALF;
  const float* Wi0 = half ? dWih0 : eWih0;
  const float* Wi  = half ? dWih  : eWih;
  const float* Wh  = half ? dWhh  : eWhh;
  int l, q, kt;
  if (f < 12) { l = 0; q = f / 3; kt = f % 3; }
  else        { int ff = f - 12; l = 1 + ff / 16; ff %= 16; q = ff / 4; kt = ff % 4; }
  const int g    = q * 64 + wv * 16 + (lane & 15);
  const int k_in = ((lane >> 4) << 3) + j;
  float v;
  if (l == 0) {
    if (kt == 0) v = (k_in < NIN) ? Wi0[g * NIN + k_in] : 0.0f;
    else         v = Wh[g * H + (kt - 1) * 32 + k_in];
  } else {
    if (kt < 2) v = Wi[((l - 1) * 256 + g) * H + kt * 32 + k_in];
    else        v = Wh[(l * 256 + g) * H + (kt - 2) * 32 + k_in];
  }
  wq[idx] = (_Float16)v;
}

// ---------------------------------------------------------------------------
__device__ __forceinline__ float rcpf(float x) { return __builtin_amdgcn_rcpf(x); }
__device__ __forceinline__ f32x4 mf(h8 a, h8 b, f32x4 c) {
  return __builtin_amdgcn_mfma_f32_16x16x32_f16(a, b, c, 0, 0, 0);
}
#define SPLAT(v) ((f32x4){(v), (v), (v), (v)})

// merged-rcp LSTM cell: 5 exp + 3 rcp (+2 clamps)
__device__ __forceinline__ float ew_one(float gi, float gf, float gg, float go,
                                        float& c) {
  gg = fminf(fmaxf(gg, -20.0f), 20.0f);
  float eni = __expf(-gi);
  float e2g = __expf(2.0f * gg);
  float enf = __expf(-gf);
  float eno = __expf(-go);
  c = c * rcpf(1.0f + enf) + (e2g - 1.0f) * rcpf((1.0f + eni) * (e2g + 1.0f));
  float cc = fminf(fmaxf(c, -20.0f), 20.0f);
  float e2c = __expf(2.0f * cc);
  return (e2c - 1.0f) * rcpf((1.0f + eno) * (e2c + 1.0f));
}

__device__ __forceinline__ void cell_ew(f32x4 g0, f32x4 g1, f32x4 g2, f32x4 g3,
                                        f32x4& c, _Float16* outbuf,
                                        int quad, int r16, int lw) {
  #pragma unroll
  for (int r = 0; r < 4; r++) {
    float cv = c[r];
    float hv = ew_one(g0[r], g1[r], g2[r], g3[r], cv);
    c[r] = cv;
    outbuf[(quad * 4 + r) * HPAD + lw * 16 + r16] = (_Float16)hv;
  }
}
__device__ __forceinline__ void fireH(const h8 (&w)[16], h8 ai0, h8 ai1,
                                      const f32x4 (&ac)[4], f32x4& c,
                                      _Float16* outbuf, int quad, int r16, int lw) {
  f32x4 g0 = mf(ai1, w[1],  mf(ai0, w[0],  ac[0]));
  f32x4 g1 = mf(ai1, w[5],  mf(ai0, w[4],  ac[1]));
  f32x4 g2 = mf(ai1, w[9],  mf(ai0, w[8],  ac[2]));
  f32x4 g3 = mf(ai1, w[13], mf(ai0, w[12], ac[3]));
  cell_ew(g0, g1, g2, g3, c, outbuf, quad, r16, lw);
}
__device__ __forceinline__ void precH(const h8 (&w)[16], h8 ar0, h8 ar1,
                                      f32x4 b, f32x4 (&ac)[4]) {
  ac[0] = mf(ar1, w[3],  mf(ar0, w[2],  SPLAT(b[0])));
  ac[1] = mf(ar1, w[7],  mf(ar0, w[6],  SPLAT(b[1])));
  ac[2] = mf(ar1, w[11], mf(ar0, w[10], SPLAT(b[2])));
  ac[3] = mf(ar1, w[15], mf(ar0, w[14], SPLAT(b[3])));
}
__device__ __forceinline__ void fire0(const h8 (&w)[12], h8 ax,
                                      const f32x4 (&ac)[4], f32x4& c,
                                      _Float16* outbuf, int quad, int r16, int lw) {
  f32x4 g0 = mf(ax, w[0], ac[0]);
  f32x4 g1 = mf(ax, w[3], ac[1]);
  f32x4 g2 = mf(ax, w[6], ac[2]);
  f32x4 g3 = mf(ax, w[9], ac[3]);
  cell_ew(g0, g1, g2, g3, c, outbuf, quad, r16, lw);
}
__device__ __forceinline__ void prec0(const h8 (&w)[12], h8 ar0, h8 ar1,
                                      f32x4 b, f32x4 (&ac)[4]) {
  ac[0] = mf(ar1, w[2],  mf(ar0, w[1],  SPLAT(b[0])));
  ac[1] = mf(ar1, w[5],  mf(ar0, w[4],  SPLAT(b[1])));
  ac[2] = mf(ar1, w[8],  mf(ar0, w[7],  SPLAT(b[2])));
  ac[3] = mf(ar1, w[11], mf(ar0, w[10], SPLAT(b[3])));
}
__device__ __forceinline__ void readA(const _Float16* buf, int r16, int quad,
                                      h8& a0, h8& a1) {
  a0 = *(const h8*)(buf + r16 * HPAD + quad * 8);
  a1 = *(const h8*)(buf + r16 * HPAD + 32 + quad * 8);
}

// ---------------------------------------------------------------------------
__global__ void __launch_bounds__(512, 2)
lstm_main(const float* __restrict__ X,
          const float* __restrict__ encb,
          const float* __restrict__ decb,
          const float* __restrict__ linb,
          const h8* __restrict__ WQ,
          float* __restrict__ out) {
  __shared__ _Float16 Hb[2][NL][2][16][HPAD];   // 36864 B
  __shared__ _Float16 Xb[2][2][16][HPAD];       //  9216 B

  const int tid  = threadIdx.x;
  const int wv   = tid >> 6;        // 0..7
  const int lane = tid & 63;
  const int quad = lane >> 4;
  const int r16  = lane & 15;
  const int grp  = wv >> 2;         // encoder col-half / decoder batch group
  const int lw   = wv & 3;          // encoder layer / decoder col-slice

  // zero LDS
  {
    float* p = (float*)&Hb[0][0][0][0][0];
    for (int i = tid; i < 9216; i += 512) p[i] = 0.0f;
    float* px = (float*)&Xb[0][0][0][0];
    for (int i = tid; i < 2304; i += 512) px[i] = 0.0f;
  }
  if (tid < BB * NIN) {
    int m = tid / NIN, ii = tid - m * NIN;
    Xb[m >> 4][0][m & 15][ii] =
        (_Float16)X[((size_t)0 * BATCH + blockIdx.x * BB + m) * NIN + ii];
  }

  // ======================= ENCODER =======================
  // wave (lw, grp): layer lw, n-tiles {q*4 + 2*grp + cc}, both batch tiles.
  h8 we[8][4];
  #pragma unroll
  for (int q = 0; q < 4; q++)
    #pragma unroll
    for (int cc = 0; cc < 2; cc++)
      #pragma unroll
      for (int kt = 0; kt < 4; kt++)
        we[q * 2 + cc][kt] =
            WQ[(PACK_H8 + PROJ_H8) +
               ((lw * 64 + (q * 4 + 2 * grp + cc) * 4 + kt) * 64 + lane)];
  float ben[8];
  #pragma unroll
  for (int q = 0; q < 4; q++)
    #pragma unroll
    for (int cc = 0; cc < 2; cc++)
      ben[q * 2 + cc] = encb[lw * 256 + q * 64 + (2 * grp + cc) * 16 + r16];

  f32x4 ce[2][2];
  ce[0][0] = SPLAT(0.f); ce[0][1] = SPLAT(0.f);
  ce[1][0] = SPLAT(0.f); ce[1][1] = SPLAT(0.f);

  // x prefetch: lw==0 waves, each covers its grp's 16 rows (96 floats)
  const int  bbE = blockIdx.x * BB + grp * 16;
  const bool pfLane = (lw == 0) && (lane < 48);
  const int  pe0 = lane * 2, pe1 = pe0 + 1;
  const int  pm0 = pe0 / NIN, pc0 = pe0 % NIN;
  const int  pm1 = pe1 / NIN, pc1 = pe1 % NIN;
  float pf0 = 0.f, pf1 = 0.f;
  if (pfLane) {
    const float* xs = X + ((size_t)1 * BATCH + bbE) * NIN;
    pf0 = xs[pe0]; pf1 = xs[pe1];
  }

  __syncthreads();

  #pragma unroll 1
  for (int i = 0; i < S_LEN + NL - 1; i++) {
    const int p = i & 1;
    const bool active = (i >= lw) && (i - lw < S_LEN);
    if (active) {
      float nf0 = 0.f, nf1 = 0.f;
      if (pfLane && (i + 2 < S_LEN)) {
        const float* xs = X + ((size_t)(i + 2) * BATCH + bbE) * NIN;
        nf0 = xs[pe0]; nf1 = xs[pe1];
      }
      #pragma unroll
      for (int mt = 0; mt < 2; mt++) {
        const _Float16* inb =
            (lw == 0) ? &Xb[mt][p][0][0] : &Hb[mt][lw - 1][p ^ 1][0][0];
        const _Float16* rcb = &Hb[mt][lw][p ^ 1][0][0];
        h8 ai0 = *(const h8*)(inb + r16 * HPAD + quad * 8);
        h8 ai1 = {};
        if (lw) ai1 = *(const h8*)(inb + r16 * HPAD + 32 + quad * 8);
        h8 ar0 = *(const h8*)(rcb + r16 * HPAD + quad * 8);
        h8 ar1 = *(const h8*)(rcb + r16 * HPAD + 32 + quad * 8);
        f32x4 a[8];
        #pragma unroll
        for (int j = 0; j < 8; j++) {
          f32x4 t = SPLAT(ben[j]);
          t = mf(ai0, we[j][0], t);
          if (lw) t = mf(ai1, we[j][1], t);
          t = mf(ar0, we[j][2], t);
          t = mf(ar1, we[j][3], t);
          a[j] = t;
        }
        _Float16* wb = &Hb[mt][lw][p][0][0];
        #pragma unroll
        for (int r = 0; r < 4; r++) {
          hh2 hv;
          #pragma unroll
          for (int cc = 0; cc < 2; cc++) {
            float cv = ce[mt][cc][r];
            hv[cc] = (_Float16)ew_one(a[cc][r], a[2 + cc][r],
                                      a[4 + cc][r], a[6 + cc][r], cv);
            ce[mt][cc][r] = cv;
          }
          // permuted layout: col c=ct*16+r16 lands at 4*r16+ct; ct=2*grp+cc
          *(hh2*)(wb + (quad * 4 + r) * HPAD + 4 * r16 + 2 * grp) = hv;
        }
      }
      if (pfLane && (i + 1 < S_LEN)) {
        Xb[grp][p ^ 1][pm0][pc0] = (_Float16)pf0;
        Xb[grp][p ^ 1][pm1][pc1] = (_Float16)pf1;
      }
      pf0 = nf0; pf1 = nf1;
    }
    bar_lgkm();
  }

  // ================== transition: encoder -> decoder ==================
  // 1) stage final h (permuted) into regs
  float hreg[16];
  #pragma unroll
  for (int u = 0; u < 16; u++) {
    int i2 = tid + u * 512;
    int c = i2 & 63, m = (i2 >> 6) & 15, l = (i2 >> 10) & 3, g = (i2 >> 12) & 1;
    hreg[u] = (float)Hb[g][l][(l + 1) & 1][m][PI(c)];
  }
  __syncthreads();
  // 2) write c into flat region aliasing Hb (32 KB)
  {
    float* cx = (float*)&Hb[0][0][0][0][0];
    #pragma unroll
    for (int mt = 0; mt < 2; mt++)
      #pragma unroll
      for (int cc = 0; cc < 2; cc++)
        #pragma unroll
        for (int r = 0; r < 4; r++)
          cx[((mt * 4 + lw) * 16 + quad * 4 + r) * 64 +
             (2 * grp + cc) * 16 + r16] = ce[mt][cc][r];
  }
  __syncthreads();
  // 3) decoder waves read their c slices
  f32x4 cs0, cs1, cs2, cs3;
  {
    const float* cx = (const float*)&Hb[0][0][0][0][0];
    #pragma unroll
    for (int r = 0; r < 4; r++) {
      cs0[r] = cx[((grp * 4 + 0) * 16 + quad * 4 + r) * 64 + lw * 16 + r16];
      cs1[r] = cx[((grp * 4 + 1) * 16 + quad * 4 + r) * 64 + lw * 16 + r16];
      cs2[r] = cx[((grp * 4 + 2) * 16 + quad * 4 + r) * 64 + lw * 16 + r16];
      cs3[r] = cx[((grp * 4 + 3) * 16 + quad * 4 + r) * 64 + lw * 16 + r16];
    }
  }
  __syncthreads();
  // 4) write unpermuted h into Hb[g][l][1]
  #pragma unroll
  for (int u = 0; u < 16; u++) {
    int i2 = tid + u * 512;
    int c = i2 & 63, m = (i2 >> 6) & 15, l = (i2 >> 10) & 3, g = (i2 >> 12) & 1;
    Hb[g][l][1][m][c] = (_Float16)hreg[u];
  }
  __syncthreads();

  // ======================= DECODER setup =======================
  const int bbase = blockIdx.x * BB + grp * 16;

  h8 w0[12], w1[16], w2[16], w3[16];
  #pragma unroll
  for (int f = 0; f < 12; f++) w0[f] = WQ[((FRAGS_HALF + f)      * 4 + lw) * 64 + lane];
  #pragma unroll
  for (int f = 0; f < 16; f++) w1[f] = WQ[((FRAGS_HALF + 12 + f) * 4 + lw) * 64 + lane];
  #pragma unroll
  for (int f = 0; f < 16; f++) w2[f] = WQ[((FRAGS_HALF + 28 + f) * 4 + lw) * 64 + lane];
  #pragma unroll
  for (int f = 0; f < 16; f++) w3[f] = WQ[((FRAGS_HALF + 44 + f) * 4 + lw) * 64 + lane];

  f32x4 b0, b1, b2, b3;
  #pragma unroll
  for (int q = 0; q < 4; q++) {
    b0[q] = decb[0 * 256 + q * 64 + lw * 16 + r16];
    b1[q] = decb[1 * 256 + q * 64 + lw * 16 + r16];
    b2[q] = decb[2 * 256 + q * 64 + lw * 16 + r16];
    b3[q] = decb[3 * 256 + q * 64 + lw * 16 + r16];
  }

  h8 lwA0 = WQ[PACK_H8 + lane];
  h8 lwA1 = WQ[PACK_H8 + 64 + lane];
  f32x4 lbq;
  #pragma unroll
  for (int r = 0; r < 4; r++)
    lbq[r] = (quad * 4 + r < NIN) ? linb[quad * 4 + r] : 0.0f;

  f32x4 ac0[4], ac1[4], ac2[4], ac3[4];
  {
    h8 s0, s1;
    readA(&Hb[grp][0][1][0][0], r16, quad, s0, s1); prec0(w0, s0, s1, b0, ac0);
    readA(&Hb[grp][1][1][0][0], r16, quad, s0, s1); precH(w1, s0, s1, b1, ac1);
    readA(&Hb[grp][2][1][0][0], r16, quad, s0, s1); precH(w2, s0, s1, b2, ac2);
  }
  __syncthreads();

  // ======================= DECODER loop =======================
  #pragma unroll 1
  for (int t = 0; t < TLEN; t++) {
    const int cur = t & 1, prv = cur ^ 1;
    // ---- interval A: proj(h3[t-1]) + layer-0 fire + acc3 precompute ----
    {
      h8 ar0, ar1;
      readA(&Hb[grp][3][prv][0][0], r16, quad, ar0, ar1);
      h8 ax;
      if (t == 0) {
        ax = *(const h8*)(&Xb[grp][1][0][0] + r16 * HPAD + quad * 8); // x[119]
      } else {
        f32x4 ap = lbq;
        ap = mf(lwA0, ar0, ap);     // A = linW (m=feature), B = h3 (n=batch)
        ap = mf(lwA1, ar1, ap);
        if (lw == 0) {
          #pragma unroll
          for (int r = 0; r < 4; r++) {
            const int fm = quad * 4 + r;
            if (fm < NIN)
              out[((size_t)(t - 1) * BATCH + bbase + r16) * NIN + fm] = ap[r];
          }
        }
        float x0 = __shfl(ap[0], r16);
        float x1 = __shfl(ap[1], r16);
        float x2 = __shfl(ap[2], r16);
        float x3 = __shfl(ap[3], r16);
        float x4 = __shfl(ap[0], 16 + r16);
        float x5 = __shfl(ap[1], 16 + r16);
        h8 xa = {};
        xa[0] = (_Float16)x0; xa[1] = (_Float16)x1; xa[2] = (_Float16)x2;
        xa[3] = (_Float16)x3; xa[4] = (_Float16)x4; xa[5] = (_Float16)x5;
        h8 zz = {};
        ax = (quad == 0) ? xa : zz;
      }
      precH(w3, ar0, ar1, b3, ac3);
      fire0(w0, ax, ac0, cs0, &Hb[grp][0][cur][0][0], quad, r16, lw);
      bar_lgkm();
    }
    // ---- interval B ----
    {
      h8 ai0, ai1;
      readA(&Hb[grp][0][cur][0][0], r16, quad, ai0, ai1);
      fireH(w1, ai0, ai1, ac1, cs1, &Hb[grp][1][cur][0][0], quad, r16, lw);
      prec0(w0, ai0, ai1, b0, ac0);
      bar_lgkm();
    }
    // ---- interval C ----
    {
      h8 ai0, ai1;
      readA(&Hb[grp][1][cur][0][0], r16, quad, ai0, ai1);
      fireH(w2, ai0, ai1, ac2, cs2, &Hb[grp][2][cur][0][0], quad, r16, lw);
      precH(w1, ai0, ai1, b1, ac1);
      bar_lgkm();
    }
    // ---- interval D ----
    {
      h8 ai0, ai1;
      readA(&Hb[grp][2][cur][0][0], r16, quad, ai0, ai1);
      fireH(w3, ai0, ai1, ac3, cs3, &Hb[grp][3][cur][0][0], quad, r16, lw);
      precH(w2, ai0, ai1, b2, ac2);
      bar_lgkm();
    }
  }

  // epilogue: out[TLEN-1] from h3 of last step (parity 1)
  if (lw == 0) {
    h8 ar0, ar1;
    readA(&Hb[grp][3][1][0][0], r16, quad, ar0, ar1);
    f32x4 ap = lbq;
    ap = mf(lwA0, ar0, ap);
    ap = mf(lwA1, ar1, ap);
    #pragma unroll
    for (int r = 0; r < 4; r++) {
      const int fm = quad * 4 + r;
      if (fm < NIN)
        out[((size_t)(TLEN - 1) * BATCH + bbase + r16) * NIN + fm] = ap[r];
    }
  }
}

// ---------------------------------------------------------------------------
extern "C" void kernel_launch(void* const* d_in, const int* in_sizes, int n_in,
                              void* d_out, int out_size, void* d_ws, size_t ws_size,
                              hipStream_t stream) {
  const float* X     = (const float*)d_in[0];
  const float* eWih0 = (const float*)d_in[1];
  const float* eWih  = (const float*)d_in[2];
  const float* eWhh  = (const float*)d_in[3];
  const float* eb    = (const float*)d_in[4];
  const float* dWih0 = (const float*)d_in[5];
  const float* dWih  = (const float*)d_in[6];
  const float* dWhh  = (const float*)d_in[7];
  const float* db    = (const float*)d_in[8];
  const float* lW    = (const float*)d_in[9];
  const float* lb    = (const float*)d_in[10];

  _Float16* wq = (_Float16*)d_ws;

  prep_weights<<<(NTOT + 255) / 256, 256, 0, stream>>>(
      eWih0, eWih, eWhh, dWih0, dWih, dWhh, lW, wq);

  lstm_main<<<BATCH / BB, 512, 0, stream>>>(
      X, eb, db, lb, (const h8*)wq, (float*)d_out);
}

// Round 9
// 842.553 us; speedup vs baseline: 2.2184x; 2.2184x over previous
//
#include <hip/hip_runtime.h>

// ---------------------------------------------------------------------------
// Round 9: two-kernel split.
//  Encoder: R8's verified wavefront pipeline (64 blocks x 512 thr, BB=32,
//    wave = (layer, col-half), 32 frags/wave, 2 waves/SIMD) -> h,c to global.
//  Decoder: R7's verified col-sliced scheme (128 blocks x 256 thr, 1 wave/SIMD,
//    512-VGPR budget) with s_barrier replaced by LDS flag sync (monotonic
//    interval counters; spin until min(flags) >= g).
// ---------------------------------------------------------------------------

#define S_LEN 120
#define BATCH 2048
#define NIN   6
#define H     64
#define NL    4
#define TLEN  120

#define HPAD 72            // row stride in halves (144 B)

#define FRAGS_HALF 60      // col-sliced: 12 (layer0) + 3*16
#define PACK_H8    (2 * FRAGS_HALF * 4 * 64)
#define PROJ_H8    (2 * 64)
#define NPACK      ((PACK_H8 + PROJ_H8) * 8)   // 246784 fp16 elements
#define EPACK_EL   (256 * 64 * 8)              // encoder pipeline pack
#define NTOT       (NPACK + EPACK_EL)          // 377856 (~756 KB)

// workspace byte offsets (after the weight pack)
#define WS_HOFF (768 * 1024)                       // h: 4*2048*64 fp16 = 1 MB
#define WS_COFF (WS_HOFF + 1024 * 1024)            // c: 4*2048*64 f32 = 2 MB

#define PERM(kk) ((((kk) & 3) << 4) | ((kk) >> 2))   // pi^-1
#define PI(c)    ((((c) & 15) << 2) | ((c) >> 4))    // pi

typedef _Float16 h8    __attribute__((ext_vector_type(8)));
typedef _Float16 hh2   __attribute__((ext_vector_type(2)));
typedef float    f32x4 __attribute__((ext_vector_type(4)));

__device__ __forceinline__ void bar_lgkm() {
  asm volatile("s_waitcnt lgkmcnt(0)\n\ts_barrier" ::: "memory");
}

// ---------------------------------------------------------------------------
// Weight pack (identical to rounds 5-8).
// ---------------------------------------------------------------------------
__global__ void prep_weights(const float* __restrict__ eWih0,
                             const float* __restrict__ eWih,
                             const float* __restrict__ eWhh,
                             const float* __restrict__ dWih0,
                             const float* __restrict__ dWih,
                             const float* __restrict__ dWhh,
                             const float* __restrict__ linW,
                             _Float16* __restrict__ wq) {
  int idx = blockIdx.x * blockDim.x + threadIdx.x;
  if (idx >= NTOT) return;

  if (idx >= NPACK) {                      // ---- encoder pipeline pack ----
    int p    = idx - NPACK;
    int j    = p & 7;
    int lane = (p >> 3) & 63;
    int fe   = p >> 9;
    int kt   = fe & 3, nt = (fe >> 2) & 15, l = fe >> 6;
    int g    = nt * 16 + (lane & 15);
    int koff = ((lane >> 4) << 3) + j;
    float v = 0.0f;
    if (l == 0) {
      if (kt == 0)      v = (koff < NIN) ? eWih0[g * NIN + koff] : 0.0f;
      else if (kt == 1) v = 0.0f;
      else { int kk = (kt - 2) * 32 + koff; v = eWhh[g * H + PERM(kk)]; }
    } else {
      if (kt < 2) { int kk = kt * 32 + koff;
                    v = eWih[((l - 1) * 256 + g) * H + PERM(kk)]; }
      else        { int kk = (kt - 2) * 32 + koff;
                    v = eWhh[(l * 256 + g) * H + PERM(kk)]; }
    }
    wq[idx] = (_Float16)v;
    return;
  }

  if (idx >= PACK_H8 * 8) {                // ---- linW A-layout frags ----
    int p    = idx - PACK_H8 * 8;
    int j    = p & 7;
    int lane = (p >> 3) & 63;
    int fr   = p >> 9;
    int m    = lane & 15;
    int k    = fr * 32 + ((lane >> 4) << 3) + j;
    wq[idx] = (_Float16)((m < NIN) ? linW[m * H + k] : 0.0f);
    return;
  }

  // ---- col-sliced pack (decoder uses dec half) ----
  const int j    = idx & 7;
  const int lane = (idx >> 3) & 63;
  const int wv   = (idx >> 9) & 3;
  const int fh   = idx >> 11;
  const int f    = fh % FRAGS_HALF;
  const int half = fh / FRAGS_HALF;
  const float* Wi0 = half ? dWih0 : eWih0;
  const float* Wi  = half ? dWih  : eWih;
  const float* Wh  = half ? dWhh  : eWhh;
  int l, q, kt;
  if (f < 12) { l = 0; q = f / 3; kt = f % 3; }
  else        { int ff = f - 12; l = 1 + ff / 16; ff %= 16; q = ff / 4; kt = ff % 4; }
  const int g    = q * 64 + wv * 16 + (lane & 15);
  const int k_in = ((lane >> 4) << 3) + j;
  float v;
  if (l == 0) {
    if (kt == 0) v = (k_in < NIN) ? Wi0[g * NIN + k_in] : 0.0f;
    else         v = Wh[g * H + (kt - 1) * 32 + k_in];
  } else {
    if (kt < 2) v = Wi[((l - 1) * 256 + g) * H + kt * 32 + k_in];
    else        v = Wh[(l * 256 + g) * H + (kt - 2) * 32 + k_in];
  }
  wq[idx] = (_Float16)v;
}

// ---------------------------------------------------------------------------
__device__ __forceinline__ float rcpf(float x) { return __builtin_amdgcn_rcpf(x); }
__device__ __forceinline__ f32x4 mf(h8 a, h8 b, f32x4 c) {
  return __builtin_amdgcn_mfma_f32_16x16x32_f16(a, b, c, 0, 0, 0);
}
#define SPLAT(v) ((f32x4){(v), (v), (v), (v)})

// merged-rcp LSTM cell: 5 exp + 3 rcp (+2 clamps); absmax-validated R6-R8.
__device__ __forceinline__ float ew_one(float gi, float gf, float gg, float go,
                                        float& c) {
  gg = fminf(fmaxf(gg, -20.0f), 20.0f);
  float eni = __expf(-gi);
  float e2g = __expf(2.0f * gg);
  float enf = __expf(-gf);
  float eno = __expf(-go);
  c = c * rcpf(1.0f + enf) + (e2g - 1.0f) * rcpf((1.0f + eni) * (e2g + 1.0f));
  float cc = fminf(fmaxf(c, -20.0f), 20.0f);
  float e2c = __expf(2.0f * cc);
  return (e2c - 1.0f) * rcpf((1.0f + eno) * (e2c + 1.0f));
}

__device__ __forceinline__ void cell_ew(f32x4 g0, f32x4 g1, f32x4 g2, f32x4 g3,
                                        f32x4& c, _Float16* outbuf,
                                        int quad, int r16, int lw) {
  #pragma unroll
  for (int r = 0; r < 4; r++) {
    float cv = c[r];
    float hv = ew_one(g0[r], g1[r], g2[r], g3[r], cv);
    c[r] = cv;
    outbuf[(quad * 4 + r) * HPAD + lw * 16 + r16] = (_Float16)hv;
  }
}
__device__ __forceinline__ void fireH(const h8 (&w)[16], h8 ai0, h8 ai1,
                                      const f32x4 (&ac)[4], f32x4& c,
                                      _Float16* outbuf, int quad, int r16, int lw) {
  f32x4 g0 = mf(ai1, w[1],  mf(ai0, w[0],  ac[0]));
  f32x4 g1 = mf(ai1, w[5],  mf(ai0, w[4],  ac[1]));
  f32x4 g2 = mf(ai1, w[9],  mf(ai0, w[8],  ac[2]));
  f32x4 g3 = mf(ai1, w[13], mf(ai0, w[12], ac[3]));
  cell_ew(g0, g1, g2, g3, c, outbuf, quad, r16, lw);
}
__device__ __forceinline__ void precH(const h8 (&w)[16], h8 ar0, h8 ar1,
                                      f32x4 b, f32x4 (&ac)[4]) {
  ac[0] = mf(ar1, w[3],  mf(ar0, w[2],  SPLAT(b[0])));
  ac[1] = mf(ar1, w[7],  mf(ar0, w[6],  SPLAT(b[1])));
  ac[2] = mf(ar1, w[11], mf(ar0, w[10], SPLAT(b[2])));
  ac[3] = mf(ar1, w[15], mf(ar0, w[14], SPLAT(b[3])));
}
__device__ __forceinline__ void fire0(const h8 (&w)[12], h8 ax,
                                      const f32x4 (&ac)[4], f32x4& c,
                                      _Float16* outbuf, int quad, int r16, int lw) {
  f32x4 g0 = mf(ax, w[0], ac[0]);
  f32x4 g1 = mf(ax, w[3], ac[1]);
  f32x4 g2 = mf(ax, w[6], ac[2]);
  f32x4 g3 = mf(ax, w[9], ac[3]);
  cell_ew(g0, g1, g2, g3, c, outbuf, quad, r16, lw);
}
__device__ __forceinline__ void prec0(const h8 (&w)[12], h8 ar0, h8 ar1,
                                      f32x4 b, f32x4 (&ac)[4]) {
  ac[0] = mf(ar1, w[2],  mf(ar0, w[1],  SPLAT(b[0])));
  ac[1] = mf(ar1, w[5],  mf(ar0, w[4],  SPLAT(b[1])));
  ac[2] = mf(ar1, w[8],  mf(ar0, w[7],  SPLAT(b[2])));
  ac[3] = mf(ar1, w[11], mf(ar0, w[10], SPLAT(b[3])));
}
__device__ __forceinline__ void readA(const _Float16* buf, int r16, int quad,
                                      h8& a0, h8& a1) {
  a0 = *(const h8*)(buf + r16 * HPAD + quad * 8);
  a1 = *(const h8*)(buf + r16 * HPAD + 32 + quad * 8);
}

// ===========================================================================
// ENCODER kernel: 64 blocks x 512 threads, BB=32. Wave (lw,grp): layer lw,
// col-half grp, both 16-batch tiles. 2 waves/SIMD fill stalls. Ends by
// storing h (plain layout) and c to global workspace.
// ===========================================================================
__global__ void __launch_bounds__(512, 2)
lstm_enc(const float* __restrict__ X,
         const float* __restrict__ encb,
         const h8* __restrict__ WQ,
         _Float16* __restrict__ hG,
         float* __restrict__ cG) {
  __shared__ _Float16 Hb[2][NL][2][16][HPAD];   // 36864 B
  __shared__ _Float16 Xb[2][2][16][HPAD];       //  9216 B

  const int tid  = threadIdx.x;
  const int wv   = tid >> 6;
  const int lane = tid & 63;
  const int quad = lane >> 4;
  const int r16  = lane & 15;
  const int grp  = wv >> 2;
  const int lw   = wv & 3;

  {
    float* p = (float*)&Hb[0][0][0][0][0];
    for (int i = tid; i < 9216; i += 512) p[i] = 0.0f;
    float* px = (float*)&Xb[0][0][0][0];
    for (int i = tid; i < 2304; i += 512) px[i] = 0.0f;
  }
  if (tid < 32 * NIN) {
    int m = tid / NIN, ii = tid - m * NIN;
    Xb[m >> 4][0][m & 15][ii] =
        (_Float16)X[((size_t)0 * BATCH + blockIdx.x * 32 + m) * NIN + ii];
  }

  h8 we[8][4];
  #pragma unroll
  for (int q = 0; q < 4; q++)
    #pragma unroll
    for (int cc = 0; cc < 2; cc++)
      #pragma unroll
      for (int kt = 0; kt < 4; kt++)
        we[q * 2 + cc][kt] =
            WQ[(PACK_H8 + PROJ_H8) +
               ((lw * 64 + (q * 4 + 2 * grp + cc) * 4 + kt) * 64 + lane)];
  float ben[8];
  #pragma unroll
  for (int q = 0; q < 4; q++)
    #pragma unroll
    for (int cc = 0; cc < 2; cc++)
      ben[q * 2 + cc] = encb[lw * 256 + q * 64 + (2 * grp + cc) * 16 + r16];

  f32x4 ce[2][2];
  ce[0][0] = SPLAT(0.f); ce[0][1] = SPLAT(0.f);
  ce[1][0] = SPLAT(0.f); ce[1][1] = SPLAT(0.f);

  const int  bbE = blockIdx.x * 32 + grp * 16;
  const bool pfLane = (lw == 0) && (lane < 48);
  const int  pe0 = lane * 2, pe1 = pe0 + 1;
  const int  pm0 = pe0 / NIN, pc0 = pe0 % NIN;
  const int  pm1 = pe1 / NIN, pc1 = pe1 % NIN;
  float pf0 = 0.f, pf1 = 0.f;
  if (pfLane) {
    const float* xs = X + ((size_t)1 * BATCH + bbE) * NIN;
    pf0 = xs[pe0]; pf1 = xs[pe1];
  }

  __syncthreads();

  #pragma unroll 1
  for (int i = 0; i < S_LEN + NL - 1; i++) {
    const int p = i & 1;
    const bool active = (i >= lw) && (i - lw < S_LEN);
    if (active) {
      float nf0 = 0.f, nf1 = 0.f;
      if (pfLane && (i + 2 < S_LEN)) {
        const float* xs = X + ((size_t)(i + 2) * BATCH + bbE) * NIN;
        nf0 = xs[pe0]; nf1 = xs[pe1];
      }
      #pragma unroll
      for (int mt = 0; mt < 2; mt++) {
        const _Float16* inb =
            (lw == 0) ? &Xb[mt][p][0][0] : &Hb[mt][lw - 1][p ^ 1][0][0];
        const _Float16* rcb = &Hb[mt][lw][p ^ 1][0][0];
        h8 ai0 = *(const h8*)(inb + r16 * HPAD + quad * 8);
        h8 ai1 = {};
        if (lw) ai1 = *(const h8*)(inb + r16 * HPAD + 32 + quad * 8);
        h8 ar0 = *(const h8*)(rcb + r16 * HPAD + quad * 8);
        h8 ar1 = *(const h8*)(rcb + r16 * HPAD + 32 + quad * 8);
        f32x4 a[8];
        #pragma unroll
        for (int j = 0; j < 8; j++) {
          f32x4 t = SPLAT(ben[j]);
          t = mf(ai0, we[j][0], t);
          if (lw) t = mf(ai1, we[j][1], t);
          t = mf(ar0, we[j][2], t);
          t = mf(ar1, we[j][3], t);
          a[j] = t;
        }
        _Float16* wb = &Hb[mt][lw][p][0][0];
        #pragma unroll
        for (int r = 0; r < 4; r++) {
          hh2 hv;
          #pragma unroll
          for (int cc = 0; cc < 2; cc++) {
            float cv = ce[mt][cc][r];
            hv[cc] = (_Float16)ew_one(a[cc][r], a[2 + cc][r],
                                      a[4 + cc][r], a[6 + cc][r], cv);
            ce[mt][cc][r] = cv;
          }
          *(hh2*)(wb + (quad * 4 + r) * HPAD + 4 * r16 + 2 * grp) = hv;
        }
      }
      if (pfLane && (i + 1 < S_LEN)) {
        Xb[grp][p ^ 1][pm0][pc0] = (_Float16)pf0;
        Xb[grp][p ^ 1][pm1][pc1] = (_Float16)pf1;
      }
      pf0 = nf0; pf1 = nf1;
    }
    bar_lgkm();
  }

  // ---- store c to global (per-lane direct) ----
  #pragma unroll
  for (int mt = 0; mt < 2; mt++)
    #pragma unroll
    for (int cc = 0; cc < 2; cc++)
      #pragma unroll
      for (int r = 0; r < 4; r++)
        cG[((size_t)lw * BATCH + blockIdx.x * 32 + mt * 16 + quad * 4 + r) * H +
           (2 * grp + cc) * 16 + r16] = ce[mt][cc][r];

  // ---- store final h (unpermute via PI) to global ----
  #pragma unroll
  for (int u = 0; u < 16; u++) {
    int i2 = tid + u * 512;
    int c = i2 & 63, m = (i2 >> 6) & 15, l = (i2 >> 10) & 3, g2 = (i2 >> 12) & 1;
    hG[((size_t)l * BATCH + blockIdx.x * 32 + g2 * 16 + m) * H + c] =
        Hb[g2][l][(l + 1) & 1][m][PI(c)];
  }
}

// ===========================================================================
// DECODER kernel: 128 blocks x 256 threads (1 wave/SIMD, full VGPR budget).
// R7 col-sliced structure; s_barrier replaced by LDS flag sync.
// ===========================================================================
__global__ void __launch_bounds__(256, 1)
lstm_dec(const float* __restrict__ X,
         const float* __restrict__ decb,
         const float* __restrict__ linb,
         const h8* __restrict__ WQ,
         const _Float16* __restrict__ hG,
         const float* __restrict__ cG,
         float* __restrict__ out) {
  __shared__ _Float16 Hb[NL][2][16][HPAD];   // 18432 B
  __shared__ unsigned flgS[4];

  const int tid   = threadIdx.x;
  const int lw    = tid >> 6;
  const int lane  = tid & 63;
  const int quad  = lane >> 4;
  const int r16   = lane & 15;
  const int bbase = blockIdx.x * 16;
  volatile unsigned* flg = flgS;

  if (tid < 4) flgS[tid] = 0;

  // load encoder-final h into Hb[l][1]
  #pragma unroll
  for (int u = 0; u < 16; u++) {
    int i2 = tid + u * 256;
    int l = i2 >> 10, m = (i2 >> 6) & 15, c = i2 & 63;
    Hb[l][1][m][c] = hG[((size_t)l * BATCH + bbase + m) * H + c];
  }

  // c slices
  f32x4 cs0, cs1, cs2, cs3;
  #pragma unroll
  for (int r = 0; r < 4; r++) {
    cs0[r] = cG[((size_t)0 * BATCH + bbase + quad * 4 + r) * H + lw * 16 + r16];
    cs1[r] = cG[((size_t)1 * BATCH + bbase + quad * 4 + r) * H + lw * 16 + r16];
    cs2[r] = cG[((size_t)2 * BATCH + bbase + quad * 4 + r) * H + lw * 16 + r16];
    cs3[r] = cG[((size_t)3 * BATCH + bbase + quad * 4 + r) * H + lw * 16 + r16];
  }

  // weights + biases
  h8 w0[12], w1[16], w2[16], w3[16];
  #pragma unroll
  for (int f = 0; f < 12; f++) w0[f] = WQ[((FRAGS_HALF + f)      * 4 + lw) * 64 + lane];
  #pragma unroll
  for (int f = 0; f < 16; f++) w1[f] = WQ[((FRAGS_HALF + 12 + f) * 4 + lw) * 64 + lane];
  #pragma unroll
  for (int f = 0; f < 16; f++) w2[f] = WQ[((FRAGS_HALF + 28 + f) * 4 + lw) * 64 + lane];
  #pragma unroll
  for (int f = 0; f < 16; f++) w3[f] = WQ[((FRAGS_HALF + 44 + f) * 4 + lw) * 64 + lane];

  f32x4 b0, b1, b2, b3;
  #pragma unroll
  for (int q = 0; q < 4; q++) {
    b0[q] = decb[0 * 256 + q * 64 + lw * 16 + r16];
    b1[q] = decb[1 * 256 + q * 64 + lw * 16 + r16];
    b2[q] = decb[2 * 256 + q * 64 + lw * 16 + r16];
    b3[q] = decb[3 * 256 + q * 64 + lw * 16 + r16];
  }

  h8 lwA0 = WQ[PACK_H8 + lane];
  h8 lwA1 = WQ[PACK_H8 + 64 + lane];
  f32x4 lbq;
  #pragma unroll
  for (int r = 0; r < 4; r++)
    lbq[r] = (quad * 4 + r < NIN) ? linb[quad * 4 + r] : 0.0f;

  // x[119] A-frag (k = quad*8+j; only k<6 real)
  h8 xseed = {};
  if (quad == 0) {
    const float* xs = X + ((size_t)(S_LEN - 1) * BATCH + bbase + r16) * NIN;
    #pragma unroll
    for (int j = 0; j < 6; j++) xseed[j] = (_Float16)xs[j];
  }

  __syncthreads();   // h-load + flag init visible

  // seed accumulators from encoder-final h
  f32x4 ac0[4], ac1[4], ac2[4], ac3[4];
  {
    h8 s0, s1;
    readA(&Hb[0][1][0][0], r16, quad, s0, s1); prec0(w0, s0, s1, b0, ac0);
    readA(&Hb[1][1][0][0], r16, quad, s0, s1); precH(w1, s0, s1, b1, ac1);
    readA(&Hb[2][1][0][0], r16, quad, s0, s1); precH(w2, s0, s1, b2, ac2);
  }

  unsigned g = 1;
  #pragma unroll 1
  for (int t = 0; t < TLEN; t++) {
    const int cur = t & 1, prv = cur ^ 1;
    // ---- interval A: proj(h3[t-1]) + layer-0 fire + acc3 precompute ----
    {
      h8 ar0, ar1;
      readA(&Hb[3][prv][0][0], r16, quad, ar0, ar1);
      h8 ax;
      if (t == 0) {
        ax = xseed;
      } else {
        f32x4 ap = lbq;
        ap = mf(lwA0, ar0, ap);     // A = linW (m=feature), B = h3 (n=batch)
        ap = mf(lwA1, ar1, ap);
        if (lw == 0) {
          #pragma unroll
          for (int r = 0; r < 4; r++) {
            const int fm = quad * 4 + r;
            if (fm < NIN)
              out[((size_t)(t - 1) * BATCH + bbase + r16) * NIN + fm] = ap[r];
          }
        }
        float x0 = __shfl(ap[0], r16);
        float x1 = __shfl(ap[1], r16);
        float x2 = __shfl(ap[2], r16);
        float x3 = __shfl(ap[3], r16);
        float x4 = __shfl(ap[0], 16 + r16);
        float x5 = __shfl(ap[1], 16 + r16);
        h8 xa = {};
        xa[0] = (_Float16)x0; xa[1] = (_Float16)x1; xa[2] = (_Float16)x2;
        xa[3] = (_Float16)x3; xa[4] = (_Float16)x4; xa[5] = (_Float16)x5;
        h8 zz = {};
        ax = (quad == 0) ? xa : zz;
      }
      precH(w3, ar0, ar1, b3, ac3);
      fire0(w0, ax, ac0, cs0, &Hb[0][cur][0][0], quad, r16, lw);
      // flag sync
      asm volatile("s_waitcnt lgkmcnt(0)" ::: "memory");
      if (lane == 0) flg[lw] = g;
      { unsigned a, b, c, d;
        do { a = flg[0]; b = flg[1]; c = flg[2]; d = flg[3]; }
        while (a < g || b < g || c < g || d < g); }
      asm volatile("s_waitcnt lgkmcnt(0)" ::: "memory");
      g++;
    }
    // ---- interval B ----
    {
      h8 ai0, ai1;
      readA(&Hb[0][cur][0][0], r16, quad, ai0, ai1);
      fireH(w1, ai0, ai1, ac1, cs1, &Hb[1][cur][0][0], quad, r16, lw);
      prec0(w0, ai0, ai1, b0, ac0);
      asm volatile("s_waitcnt lgkmcnt(0)" ::: "memory");
      if (lane == 0) flg[lw] = g;
      { unsigned a, b, c, d;
        do { a = flg[0]; b = flg[1]; c = flg[2]; d = flg[3]; }
        while (a < g || b < g || c < g || d < g); }
      asm volatile("s_waitcnt lgkmcnt(0)" ::: "memory");
      g++;
    }
    // ---- interval C ----
    {
      h8 ai0, ai1;
      readA(&Hb[1][cur][0][0], r16, quad, ai0, ai1);
      fireH(w2, ai0, ai1, ac2, cs2, &Hb[2][cur][0][0], quad, r16, lw);
      precH(w1, ai0, ai1, b1, ac1);
      asm volatile("s_waitcnt lgkmcnt(0)" ::: "memory");
      if (lane == 0) flg[lw] = g;
      { unsigned a, b, c, d;
        do { a = flg[0]; b = flg[1]; c = flg[2]; d = flg[3]; }
        while (a < g || b < g || c < g || d < g); }
      asm volatile("s_waitcnt lgkmcnt(0)" ::: "memory");
      g++;
    }
    // ---- interval D ----
    {
      h8 ai0, ai1;
      readA(&Hb[2][cur][0][0], r16, quad, ai0, ai1);
      fireH(w3, ai0, ai1, ac3, cs3, &Hb[3][cur][0][0], quad, r16, lw);
      precH(w2, ai0, ai1, b2, ac2);
      asm volatile("s_waitcnt lgkmcnt(0)" ::: "memory");
      if (lane == 0) flg[lw] = g;
      { unsigned a, b, c, d;
        do { a = flg[0]; b = flg[1]; c = flg[2]; d = flg[3]; }
        while (a < g || b < g || c < g || d < g); }
      asm volatile("s_waitcnt lgkmcnt(0)" ::: "memory");
      g++;
    }
  }

  // epilogue: out[TLEN-1] from h3 of last step (parity 1)
  if (lw == 0) {
    h8 ar0, ar1;
    readA(&Hb[3][1][0][0], r16, quad, ar0, ar1);
    f32x4 ap = lbq;
    ap = mf(lwA0, ar0, ap);
    ap = mf(lwA1, ar1, ap);
    #pragma unroll
    for (int r = 0; r < 4; r++) {
      const int fm = quad * 4 + r;
      if (fm < NIN)
        out[((size_t)(TLEN - 1) * BATCH + bbase + r16) * NIN + fm] = ap[r];
    }
  }
}

// ---------------------------------------------------------------------------
extern "C" void kernel_launch(void* const* d_in, const int* in_sizes, int n_in,
                              void* d_out, int out_size, void* d_ws, size_t ws_size,
                              hipStream_t stream) {
  const float* X     = (const float*)d_in[0];
  const float* eWih0 = (const float*)d_in[1];
  const float* eWih  = (const float*)d_in[2];
  const float* eWhh  = (const float*)d_in[3];
  const float* eb    = (const float*)d_in[4];
  const float* dWih0 = (const float*)d_in[5];
  const float* dWih  = (const float*)d_in[6];
  const float* dWhh  = (const float*)d_in[7];
  const float* db    = (const float*)d_in[8];
  const float* lW    = (const float*)d_in[9];
  const float* lb    = (const float*)d_in[10];

  _Float16* wq = (_Float16*)d_ws;
  _Float16* hG = (_Float16*)((char*)d_ws + WS_HOFF);
  float*    cG = (float*)((char*)d_ws + WS_COFF);

  prep_weights<<<(NTOT + 255) / 256, 256, 0, stream>>>(
      eWih0, eWih, eWhh, dWih0, dWih, dWhh, lW, wq);

  lstm_enc<<<BATCH / 32, 512, 0, stream>>>(
      X, eb, (const h8*)wq, hG, cG);

  lstm_dec<<<BATCH / 16, 256, 0, stream>>>(
      X, db, lb, (const h8*)wq, hG, cG, (float*)d_out);
}

// Round 10
// 566.041 us; speedup vs baseline: 3.3020x; 1.4885x over previous
//
#include <hip/hip_runtime.h>

// ---------------------------------------------------------------------------
// Round 10: right-sized two-kernel split.
//  Encoder: 128 blocks x 512 thr, BB=16. Wave (lw,grp) = layer x col-half,
//    32 frags/wave, 2 waves/SIMD (independent col-halves fill stalls).
//  Decoder: R7/R9-validated col-sliced scheme, 128 blocks x 256 thr,
//    1 wave/SIMD (full VGPR budget), s_barrier (bar_lgkm) sync.
// ---------------------------------------------------------------------------

#define S_LEN 120
#define BATCH 2048
#define NIN   6
#define H     64
#define NL    4
#define TLEN  120

#define HPAD 72            // row stride in halves (144 B)

#define FRAGS_HALF 60      // col-sliced: 12 (layer0) + 3*16
#define PACK_H8    (2 * FRAGS_HALF * 4 * 64)
#define PROJ_H8    (2 * 64)
#define NPACK      ((PACK_H8 + PROJ_H8) * 8)   // 246784 fp16 elements
#define EPACK_EL   (256 * 64 * 8)              // encoder pipeline pack
#define NTOT       (NPACK + EPACK_EL)          // 377856 (~756 KB)

// workspace byte offsets (after the weight pack)
#define WS_HOFF (768 * 1024)                   // h: 4*2048*64 fp16 = 1 MB
#define WS_COFF (WS_HOFF + 1024 * 1024)        // c: 4*2048*64 f32 = 2 MB

#define PERM(kk) ((((kk) & 3) << 4) | ((kk) >> 2))   // pi^-1
#define PI(c)    ((((c) & 15) << 2) | ((c) >> 4))    // pi

typedef _Float16 h8    __attribute__((ext_vector_type(8)));
typedef _Float16 hh2   __attribute__((ext_vector_type(2)));
typedef float    f32x4 __attribute__((ext_vector_type(4)));

__device__ __forceinline__ void bar_lgkm() {
  asm volatile("s_waitcnt lgkmcnt(0)\n\ts_barrier" ::: "memory");
}

// ---------------------------------------------------------------------------
// Weight pack (identical to rounds 5-9).
// ---------------------------------------------------------------------------
__global__ void prep_weights(const float* __restrict__ eWih0,
                             const float* __restrict__ eWih,
                             const float* __restrict__ eWhh,
                             const float* __restrict__ dWih0,
                             const float* __restrict__ dWih,
                             const float* __restrict__ dWhh,
                             const float* __restrict__ linW,
                             _Float16* __restrict__ wq) {
  int idx = blockIdx.x * blockDim.x + threadIdx.x;
  if (idx >= NTOT) return;

  if (idx >= NPACK) {                      // ---- encoder pipeline pack ----
    int p    = idx - NPACK;
    int j    = p & 7;
    int lane = (p >> 3) & 63;
    int fe   = p >> 9;
    int kt   = fe & 3, nt = (fe >> 2) & 15, l = fe >> 6;
    int g    = nt * 16 + (lane & 15);
    int koff = ((lane >> 4) << 3) + j;
    float v = 0.0f;
    if (l == 0) {
      if (kt == 0)      v = (koff < NIN) ? eWih0[g * NIN + koff] : 0.0f;
      else if (kt == 1) v = 0.0f;
      else { int kk = (kt - 2) * 32 + koff; v = eWhh[g * H + PERM(kk)]; }
    } else {
      if (kt < 2) { int kk = kt * 32 + koff;
                    v = eWih[((l - 1) * 256 + g) * H + PERM(kk)]; }
      else        { int kk = (kt - 2) * 32 + koff;
                    v = eWhh[(l * 256 + g) * H + PERM(kk)]; }
    }
    wq[idx] = (_Float16)v;
    return;
  }

  if (idx >= PACK_H8 * 8) {                // ---- linW A-layout frags ----
    int p    = idx - PACK_H8 * 8;
    int j    = p & 7;
    int lane = (p >> 3) & 63;
    int fr   = p >> 9;
    int m    = lane & 15;
    int k    = fr * 32 + ((lane >> 4) << 3) + j;
    wq[idx] = (_Float16)((m < NIN) ? linW[m * H + k] : 0.0f);
    return;
  }

  // ---- col-sliced pack (decoder uses dec half) ----
  const int j    = idx & 7;
  const int lane = (idx >> 3) & 63;
  const int wv   = (idx >> 9) & 3;
  const int fh   = idx >> 11;
  const int f    = fh % FRAGS_HALF;
  const int half = fh / FRAGS_HALF;
  const float* Wi0 = half ? dWih0 : eWih0;
  const float* Wi  = half ? dWih  : eWih;
  const float* Wh  = half ? dWhh  : eWhh;
  int l, q, kt;
  if (f < 12) { l = 0; q = f / 3; kt = f % 3; }
  else        { int ff = f - 12; l = 1 + ff / 16; ff %= 16; q = ff / 4; kt = ff % 4; }
  const int g    = q * 64 + wv * 16 + (lane & 15);
  const int k_in = ((lane >> 4) << 3) + j;
  float v;
  if (l == 0) {
    if (kt == 0) v = (k_in < NIN) ? Wi0[g * NIN + k_in] : 0.0f;
    else         v = Wh[g * H + (kt - 1) * 32 + k_in];
  } else {
    if (kt < 2) v = Wi[((l - 1) * 256 + g) * H + kt * 32 + k_in];
    else        v = Wh[(l * 256 + g) * H + (kt - 2) * 32 + k_in];
  }
  wq[idx] = (_Float16)v;
}

// ---------------------------------------------------------------------------
__device__ __forceinline__ float rcpf(float x) { return __builtin_amdgcn_rcpf(x); }
__device__ __forceinline__ f32x4 mf(h8 a, h8 b, f32x4 c) {
  return __builtin_amdgcn_mfma_f32_16x16x32_f16(a, b, c, 0, 0, 0);
}
#define SPLAT(v) ((f32x4){(v), (v), (v), (v)})

// merged-rcp LSTM cell: 5 exp + 3 rcp (+2 clamps); absmax-validated R6-R9.
__device__ __forceinline__ float ew_one(float gi, float gf, float gg, float go,
                                        float& c) {
  gg = fminf(fmaxf(gg, -20.0f), 20.0f);
  float eni = __expf(-gi);
  float e2g = __expf(2.0f * gg);
  float enf = __expf(-gf);
  float eno = __expf(-go);
  c = c * rcpf(1.0f + enf) + (e2g - 1.0f) * rcpf((1.0f + eni) * (e2g + 1.0f));
  float cc = fminf(fmaxf(c, -20.0f), 20.0f);
  float e2c = __expf(2.0f * cc);
  return (e2c - 1.0f) * rcpf((1.0f + eno) * (e2c + 1.0f));
}

__device__ __forceinline__ void cell_ew(f32x4 g0, f32x4 g1, f32x4 g2, f32x4 g3,
                                        f32x4& c, _Float16* outbuf,
                                        int quad, int r16, int lw) {
  #pragma unroll
  for (int r = 0; r < 4; r++) {
    float cv = c[r];
    float hv = ew_one(g0[r], g1[r], g2[r], g3[r], cv);
    c[r] = cv;
    outbuf[(quad * 4 + r) * HPAD + lw * 16 + r16] = (_Float16)hv;
  }
}
__device__ __forceinline__ void fireH(const h8 (&w)[16], h8 ai0, h8 ai1,
                                      const f32x4 (&ac)[4], f32x4& c,
                                      _Float16* outbuf, int quad, int r16, int lw) {
  f32x4 g0 = mf(ai1, w[1],  mf(ai0, w[0],  ac[0]));
  f32x4 g1 = mf(ai1, w[5],  mf(ai0, w[4],  ac[1]));
  f32x4 g2 = mf(ai1, w[9],  mf(ai0, w[8],  ac[2]));
  f32x4 g3 = mf(ai1, w[13], mf(ai0, w[12], ac[3]));
  cell_ew(g0, g1, g2, g3, c, outbuf, quad, r16, lw);
}
__device__ __forceinline__ void precH(const h8 (&w)[16], h8 ar0, h8 ar1,
                                      f32x4 b, f32x4 (&ac)[4]) {
  ac[0] = mf(ar1, w[3],  mf(ar0, w[2],  SPLAT(b[0])));
  ac[1] = mf(ar1, w[7],  mf(ar0, w[6],  SPLAT(b[1])));
  ac[2] = mf(ar1, w[11], mf(ar0, w[10], SPLAT(b[2])));
  ac[3] = mf(ar1, w[15], mf(ar0, w[14], SPLAT(b[3])));
}
__device__ __forceinline__ void fire0(const h8 (&w)[12], h8 ax,
                                      const f32x4 (&ac)[4], f32x4& c,
                                      _Float16* outbuf, int quad, int r16, int lw) {
  f32x4 g0 = mf(ax, w[0], ac[0]);
  f32x4 g1 = mf(ax, w[3], ac[1]);
  f32x4 g2 = mf(ax, w[6], ac[2]);
  f32x4 g3 = mf(ax, w[9], ac[3]);
  cell_ew(g0, g1, g2, g3, c, outbuf, quad, r16, lw);
}
__device__ __forceinline__ void prec0(const h8 (&w)[12], h8 ar0, h8 ar1,
                                      f32x4 b, f32x4 (&ac)[4]) {
  ac[0] = mf(ar1, w[2],  mf(ar0, w[1],  SPLAT(b[0])));
  ac[1] = mf(ar1, w[5],  mf(ar0, w[4],  SPLAT(b[1])));
  ac[2] = mf(ar1, w[8],  mf(ar0, w[7],  SPLAT(b[2])));
  ac[3] = mf(ar1, w[11], mf(ar0, w[10], SPLAT(b[3])));
}
__device__ __forceinline__ void readA(const _Float16* buf, int r16, int quad,
                                      h8& a0, h8& a1) {
  a0 = *(const h8*)(buf + r16 * HPAD + quad * 8);
  a1 = *(const h8*)(buf + r16 * HPAD + 32 + quad * 8);
}

// ===========================================================================
// ENCODER kernel: 128 blocks x 512 threads, BB=16.
// Wave (lw,grp): layer lw, col-half grp (8 n-tiles x 4 kt = 32 frags).
// 2 waves/SIMD; SIMD pairs are independent col-halves of the same layer.
// Ends by storing h (plain layout) and c to global workspace.
// ===========================================================================
__global__ void __launch_bounds__(512, 2)
lstm_enc(const float* __restrict__ X,
         const float* __restrict__ encb,
         const h8* __restrict__ WQ,
         _Float16* __restrict__ hG,
         float* __restrict__ cG) {
  __shared__ _Float16 Hb[NL][2][16][HPAD];   // 18432 B
  __shared__ _Float16 Xb[2][16][HPAD];       //  4608 B

  const int tid  = threadIdx.x;
  const int wv   = tid >> 6;        // 0..7
  const int lane = tid & 63;
  const int quad = lane >> 4;
  const int r16  = lane & 15;
  const int grp  = wv >> 2;         // col-half
  const int lw   = wv & 3;          // layer
  const int bbase = blockIdx.x * 16;

  {
    float* p = (float*)&Hb[0][0][0][0];
    for (int i = tid; i < 4608; i += 512) p[i] = 0.0f;
    float* px = (float*)&Xb[0][0][0];
    for (int i = tid; i < 1152; i += 512) if (i < 1152) px[i] = 0.0f;
  }
  if (tid < 16 * NIN) {
    int m = tid / NIN, ii = tid - m * NIN;
    Xb[0][m][ii] = (_Float16)X[((size_t)0 * BATCH + bbase + m) * NIN + ii];
  }

  // weights: 8 n-tiles {q*4 + 2*grp + cc}, 4 k-tiles each
  h8 we[8][4];
  #pragma unroll
  for (int q = 0; q < 4; q++)
    #pragma unroll
    for (int cc = 0; cc < 2; cc++)
      #pragma unroll
      for (int kt = 0; kt < 4; kt++)
        we[q * 2 + cc][kt] =
            WQ[(PACK_H8 + PROJ_H8) +
               ((lw * 64 + (q * 4 + 2 * grp + cc) * 4 + kt) * 64 + lane)];
  float ben[8];
  #pragma unroll
  for (int q = 0; q < 4; q++)
    #pragma unroll
    for (int cc = 0; cc < 2; cc++)
      ben[q * 2 + cc] = encb[lw * 256 + q * 64 + (2 * grp + cc) * 16 + r16];

  f32x4 ce[2];
  ce[0] = SPLAT(0.f); ce[1] = SPLAT(0.f);

  // 2-deep x prefetch: wave (lw=0, grp=0), lanes 0..47, 2 floats each
  const bool pfLane = (wv == 0) && (lane < 48);
  const int  pe0 = lane * 2, pe1 = pe0 + 1;
  const int  pm0 = pe0 / NIN, pc0 = pe0 % NIN;
  const int  pm1 = pe1 / NIN, pc1 = pe1 % NIN;
  float pf0 = 0.f, pf1 = 0.f;
  if (pfLane) {
    const float* xs = X + ((size_t)1 * BATCH + bbase) * NIN;
    pf0 = xs[pe0]; pf1 = xs[pe1];
  }

  __syncthreads();

  #pragma unroll 1
  for (int i = 0; i < S_LEN + NL - 1; i++) {     // 123 intervals
    const int p = i & 1;
    const bool active = (i >= lw) && (i - lw < S_LEN);
    if (active) {
      const _Float16* inb = (lw == 0) ? &Xb[p][0][0] : &Hb[lw - 1][p ^ 1][0][0];
      const _Float16* rcb = &Hb[lw][p ^ 1][0][0];
      h8 ai0 = *(const h8*)(inb + r16 * HPAD + quad * 8);
      h8 ai1 = {};
      if (lw) ai1 = *(const h8*)(inb + r16 * HPAD + 32 + quad * 8);
      h8 ar0 = *(const h8*)(rcb + r16 * HPAD + quad * 8);
      h8 ar1 = *(const h8*)(rcb + r16 * HPAD + 32 + quad * 8);

      float nf0 = 0.f, nf1 = 0.f;
      if (pfLane && (i + 2 < S_LEN)) {
        const float* xs = X + ((size_t)(i + 2) * BATCH + bbase) * NIN;
        nf0 = xs[pe0]; nf1 = xs[pe1];
      }

      f32x4 a[8];
      #pragma unroll
      for (int j = 0; j < 8; j++) {
        f32x4 t = SPLAT(ben[j]);
        t = mf(ai0, we[j][0], t);
        if (lw) t = mf(ai1, we[j][1], t);
        t = mf(ar0, we[j][2], t);
        t = mf(ar1, we[j][3], t);
        a[j] = t;
      }

      _Float16* wb = &Hb[lw][p][0][0];
      #pragma unroll
      for (int r = 0; r < 4; r++) {
        hh2 hv;
        #pragma unroll
        for (int cc = 0; cc < 2; cc++) {
          float cv = ce[cc][r];
          hv[cc] = (_Float16)ew_one(a[cc][r], a[2 + cc][r],
                                    a[4 + cc][r], a[6 + cc][r], cv);
          ce[cc][r] = cv;
        }
        // permuted layout: col c = ct*16+r16 lands at 4*r16+ct; ct = 2*grp+cc
        *(hh2*)(wb + (quad * 4 + r) * HPAD + 4 * r16 + 2 * grp) = hv;
      }

      if (pfLane && (i + 1 < S_LEN)) {
        Xb[p ^ 1][pm0][pc0] = (_Float16)pf0;
        Xb[p ^ 1][pm1][pc1] = (_Float16)pf1;
      }
      pf0 = nf0; pf1 = nf1;
    }
    bar_lgkm();
  }

  // ---- store c to global (per-lane direct) ----
  #pragma unroll
  for (int cc = 0; cc < 2; cc++)
    #pragma unroll
    for (int r = 0; r < 4; r++)
      cG[((size_t)lw * BATCH + bbase + quad * 4 + r) * H +
         (2 * grp + cc) * 16 + r16] = ce[cc][r];

  // ---- store final h (unpermute via PI) to global ----
  #pragma unroll
  for (int u = 0; u < 8; u++) {
    int i2 = tid + u * 512;
    int c = i2 & 63, m = (i2 >> 6) & 15, l = (i2 >> 10) & 3;
    hG[((size_t)l * BATCH + bbase + m) * H + c] =
        Hb[l][(l + 1) & 1][m][PI(c)];
  }
}

// ===========================================================================
// DECODER kernel: 128 blocks x 256 threads (1 wave/SIMD, full VGPR budget).
// R7/R9-validated col-sliced structure, bar_lgkm sync (flag-spin removed).
// ===========================================================================
__global__ void __launch_bounds__(256, 1)
lstm_dec(const float* __restrict__ X,
         const float* __restrict__ decb,
         const float* __restrict__ linb,
         const h8* __restrict__ WQ,
         const _Float16* __restrict__ hG,
         const float* __restrict__ cG,
         float* __restrict__ out) {
  __shared__ _Float16 Hb[NL][2][16][HPAD];   // 18432 B

  const int tid   = threadIdx.x;
  const int lw    = tid >> 6;
  const int lane  = tid & 63;
  const int quad  = lane >> 4;
  const int r16   = lane & 15;
  const int bbase = blockIdx.x * 16;

  // load encoder-final h into Hb[l][1]
  #pragma unroll
  for (int u = 0; u < 16; u++) {
    int i2 = tid + u * 256;
    int l = i2 >> 10, m = (i2 >> 6) & 15, c = i2 & 63;
    Hb[l][1][m][c] = hG[((size_t)l * BATCH + bbase + m) * H + c];
  }

  // c slices
  f32x4 cs0, cs1, cs2, cs3;
  #pragma unroll
  for (int r = 0; r < 4; r++) {
    cs0[r] = cG[((size_t)0 * BATCH + bbase + quad * 4 + r) * H + lw * 16 + r16];
    cs1[r] = cG[((size_t)1 * BATCH + bbase + quad * 4 + r) * H + lw * 16 + r16];
    cs2[r] = cG[((size_t)2 * BATCH + bbase + quad * 4 + r) * H + lw * 16 + r16];
    cs3[r] = cG[((size_t)3 * BATCH + bbase + quad * 4 + r) * H + lw * 16 + r16];
  }

  // weights + biases
  h8 w0[12], w1[16], w2[16], w3[16];
  #pragma unroll
  for (int f = 0; f < 12; f++) w0[f] = WQ[((FRAGS_HALF + f)      * 4 + lw) * 64 + lane];
  #pragma unroll
  for (int f = 0; f < 16; f++) w1[f] = WQ[((FRAGS_HALF + 12 + f) * 4 + lw) * 64 + lane];
  #pragma unroll
  for (int f = 0; f < 16; f++) w2[f] = WQ[((FRAGS_HALF + 28 + f) * 4 + lw) * 64 + lane];
  #pragma unroll
  for (int f = 0; f < 16; f++) w3[f] = WQ[((FRAGS_HALF + 44 + f) * 4 + lw) * 64 + lane];

  f32x4 b0, b1, b2, b3;
  #pragma unroll
  for (int q = 0; q < 4; q++) {
    b0[q] = decb[0 * 256 + q * 64 + lw * 16 + r16];
    b1[q] = decb[1 * 256 + q * 64 + lw * 16 + r16];
    b2[q] = decb[2 * 256 + q * 64 + lw * 16 + r16];
    b3[q] = decb[3 * 256 + q * 64 + lw * 16 + r16];
  }

  h8 lwA0 = WQ[PACK_H8 + lane];
  h8 lwA1 = WQ[PACK_H8 + 64 + lane];
  f32x4 lbq;
  #pragma unroll
  for (int r = 0; r < 4; r++)
    lbq[r] = (quad * 4 + r < NIN) ? linb[quad * 4 + r] : 0.0f;

  // x[119] A-frag (k = quad*8+j; only k<6 real)
  h8 xseed = {};
  if (quad == 0) {
    const float* xs = X + ((size_t)(S_LEN - 1) * BATCH + bbase + r16) * NIN;
    #pragma unroll
    for (int j = 0; j < 6; j++) xseed[j] = (_Float16)xs[j];
  }

  __syncthreads();   // h-load visible

  // seed accumulators from encoder-final h
  f32x4 ac0[4], ac1[4], ac2[4], ac3[4];
  {
    h8 s0, s1;
    readA(&Hb[0][1][0][0], r16, quad, s0, s1); prec0(w0, s0, s1, b0, ac0);
    readA(&Hb[1][1][0][0], r16, quad, s0, s1); precH(w1, s0, s1, b1, ac1);
    readA(&Hb[2][1][0][0], r16, quad, s0, s1); precH(w2, s0, s1, b2, ac2);
  }

  #pragma unroll 1
  for (int t = 0; t < TLEN; t++) {
    const int cur = t & 1, prv = cur ^ 1;
    // ---- interval A: proj(h3[t-1]) + layer-0 fire + acc3 precompute ----
    {
      h8 ar0, ar1;
      readA(&Hb[3][prv][0][0], r16, quad, ar0, ar1);
      h8 ax;
      if (t == 0) {
        ax = xseed;
      } else {
        f32x4 ap = lbq;
        ap = mf(lwA0, ar0, ap);     // A = linW (m=feature), B = h3 (n=batch)
        ap = mf(lwA1, ar1, ap);
        if (lw == 0) {
          #pragma unroll
          for (int r = 0; r < 4; r++) {
            const int fm = quad * 4 + r;
            if (fm < NIN)
              out[((size_t)(t - 1) * BATCH + bbase + r16) * NIN + fm] = ap[r];
          }
        }
        float x0 = __shfl(ap[0], r16);
        float x1 = __shfl(ap[1], r16);
        float x2 = __shfl(ap[2], r16);
        float x3 = __shfl(ap[3], r16);
        float x4 = __shfl(ap[0], 16 + r16);
        float x5 = __shfl(ap[1], 16 + r16);
        h8 xa = {};
        xa[0] = (_Float16)x0; xa[1] = (_Float16)x1; xa[2] = (_Float16)x2;
        xa[3] = (_Float16)x3; xa[4] = (_Float16)x4; xa[5] = (_Float16)x5;
        h8 zz = {};
        ax = (quad == 0) ? xa : zz;
      }
      precH(w3, ar0, ar1, b3, ac3);
      fire0(w0, ax, ac0, cs0, &Hb[0][cur][0][0], quad, r16, lw);
      bar_lgkm();
    }
    // ---- interval B ----
    {
      h8 ai0, ai1;
      readA(&Hb[0][cur][0][0], r16, quad, ai0, ai1);
      fireH(w1, ai0, ai1, ac1, cs1, &Hb[1][cur][0][0], quad, r16, lw);
      prec0(w0, ai0, ai1, b0, ac0);
      bar_lgkm();
    }
    // ---- interval C ----
    {
      h8 ai0, ai1;
      readA(&Hb[1][cur][0][0], r16, quad, ai0, ai1);
      fireH(w2, ai0, ai1, ac2, cs2, &Hb[2][cur][0][0], quad, r16, lw);
      precH(w1, ai0, ai1, b1, ac1);
      bar_lgkm();
    }
    // ---- interval D ----
    {
      h8 ai0, ai1;
      readA(&Hb[2][cur][0][0], r16, quad, ai0, ai1);
      fireH(w3, ai0, ai1, ac3, cs3, &Hb[3][cur][0][0], quad, r16, lw);
      precH(w2, ai0, ai1, b2, ac2);
      bar_lgkm();
    }
  }

  // epilogue: out[TLEN-1] from h3 of last step (parity 1)
  if (lw == 0) {
    h8 ar0, ar1;
    readA(&Hb[3][1][0][0], r16, quad, ar0, ar1);
    f32x4 ap = lbq;
    ap = mf(lwA0, ar0, ap);
    ap = mf(lwA1, ar1, ap);
    #pragma unroll
    for (int r = 0; r < 4; r++) {
      const int fm = quad * 4 + r;
      if (fm < NIN)
        out[((size_t)(TLEN - 1) * BATCH + bbase + r16) * NIN + fm] = ap[r];
    }
  }
}

// ---------------------------------------------------------------------------
extern "C" void kernel_launch(void* const* d_in, const int* in_sizes, int n_in,
                              void* d_out, int out_size, void* d_ws, size_t ws_size,
                              hipStream_t stream) {
  const float* X     = (const float*)d_in[0];
  const float* eWih0 = (const float*)d_in[1];
  const float* eWih  = (const float*)d_in[2];
  const float* eWhh  = (const float*)d_in[3];
  const float* eb    = (const float*)d_in[4];
  const float* dWih0 = (const float*)d_in[5];
  const float* dWih  = (const float*)d_in[6];
  const float* dWhh  = (const float*)d_in[7];
  const float* db    = (const float*)d_in[8];
  const float* lW    = (const float*)d_in[9];
  const float* lb    = (const float*)d_in[10];

  _Float16* wq = (_Float16*)d_ws;
  _Float16* hG = (_Float16*)((char*)d_ws + WS_HOFF);
  float*    cG = (float*)((char*)d_ws + WS_COFF);

  prep_weights<<<(NTOT + 255) / 256, 256, 0, stream>>>(
      eWih0, eWih, eWhh, dWih0, dWih, dWhh, lW, wq);

  lstm_enc<<<BATCH / 16, 512, 0, stream>>>(
      X, eb, (const h8*)wq, hG, cG);

  lstm_dec<<<BATCH / 16, 256, 0, stream>>>(
      X, db, lb, (const h8*)wq, hG, cG, (float*)d_out);
}